// Round 18
// baseline (431.732 us; speedup 1.0000x reference)
//
#include <hip/hip_runtime.h>
#include <hip/hip_bf16.h>

#define N_ 2
#define L_ 512
#define RD_ 128
#define PD_ 64
#define H_ 12
#define NL_ (N_*L_)
#define POUT_ 2016          /* 3*384 + 3*288 */
#define FEAT_ 1824
#define INF_ 100000.0f
#define ISQD_ 0.17677669529663687f   /* 1/sqrt(32) */
#define ISQ3_ 0.5773502691896258f    /* sqrt(1/3) */
#define LL_ ((size_t)L_*L_)

// ---------------------------------------------------------------------------
// K1: projection GEMM. proj[token][2016] = resf @ [Wq|Wk|Wv|Wqp|Wkp|Wvp]^T
// ---------------------------------------------------------------------------
__global__ __launch_bounds__(256) void k_proj_gemm(
    const float* __restrict__ resf,
    const float* __restrict__ Wq, const float* __restrict__ Wk, const float* __restrict__ Wv,
    const float* __restrict__ Wqp, const float* __restrict__ Wkp, const float* __restrict__ Wvp,
    float* __restrict__ proj)
{
  const int rb = blockIdx.x * 8;
  const int ob = blockIdx.y * 128;
  const int tid = threadIdx.x;
  __shared__ float xt[8*132];
  __shared__ float wt[128*132];
  {
    int r = tid >> 5, kq = (tid & 31) * 4;
    float4 v = *(const float4*)(resf + (size_t)(rb + r)*RD_ + kq);
    xt[r*132+kq]=v.x; xt[r*132+kq+1]=v.y; xt[r*132+kq+2]=v.z; xt[r*132+kq+3]=v.w;
  }
  for (int m = 0; m < 16; ++m) {
    int idx = m*256 + tid;
    int r = idx >> 5, kq = (idx & 31) * 4;
    int o = ob + r;
    float4 v;
    if (o < 384)        v = *(const float4*)(Wq  + (size_t)o*RD_ + kq);
    else if (o < 768)   v = *(const float4*)(Wk  + (size_t)(o-384)*RD_ + kq);
    else if (o < 1152)  v = *(const float4*)(Wv  + (size_t)(o-768)*RD_ + kq);
    else if (o < 1440)  v = *(const float4*)(Wqp + (size_t)(o-1152)*RD_ + kq);
    else if (o < 1728)  v = *(const float4*)(Wkp + (size_t)(o-1440)*RD_ + kq);
    else if (o < POUT_) v = *(const float4*)(Wvp + (size_t)(o-1728)*RD_ + kq);
    else                v = make_float4(0.f,0.f,0.f,0.f);
    wt[r*132+kq]=v.x; wt[r*132+kq+1]=v.y; wt[r*132+kq+2]=v.z; wt[r*132+kq+3]=v.w;
  }
  __syncthreads();
  const int tt = tid & 7, g = tid >> 3;
  float acc0=0.f, acc1=0.f, acc2=0.f, acc3=0.f;
  #pragma unroll 4
  for (int k2 = 0; k2 < RD_; k2 += 2) {
    float2 xv = *(const float2*)(xt + tt*132 + k2);
    float2 w0 = *(const float2*)(wt + (g     )*132 + k2);
    float2 w1 = *(const float2*)(wt + (g + 32)*132 + k2);
    float2 w2 = *(const float2*)(wt + (g + 64)*132 + k2);
    float2 w3 = *(const float2*)(wt + (g + 96)*132 + k2);
    acc0 += xv.x*w0.x + xv.y*w0.y;
    acc1 += xv.x*w1.x + xv.y*w1.y;
    acc2 += xv.x*w2.x + xv.y*w2.y;
    acc3 += xv.x*w3.x + xv.y*w3.y;
  }
  float* dst = proj + (size_t)(rb + tt)*POUT_ + ob;
  if (ob + g      < POUT_) dst[g]      = acc0;
  if (ob + g + 32 < POUT_) dst[g+32]   = acc1;
  if (ob + g + 64 < POUT_) dst[g+64]   = acc2;
  if (ob + g + 96 < POUT_) dst[g+96]   = acc3;
}

// ---------------------------------------------------------------------------
// K2: per-token rotate + build Q~/K~ (58-dim augmented, padded to 64)
// ---------------------------------------------------------------------------
__global__ __launch_bounds__(64) void k_rot(
    const float* __restrict__ R, const float* __restrict__ coord,
    const float* __restrict__ spc, const float* __restrict__ proj,
    float* __restrict__ qt, float* __restrict__ kt, float* __restrict__ vpg)
{
  const int t = blockIdx.x;
  const int n = t / L_, i = t % L_;
  const int tid = threadIdx.x;
  __shared__ float prow[POUT_];
  __shared__ float qpl[288], kpl[288], vpl[288];
  __shared__ float qqs[H_], kks[H_], coefs[H_];
  for (int m = tid; m < POUT_/4; m += 64)
    ((float4*)prow)[m] = *((const float4*)(proj + (size_t)t*POUT_) + m);
  if (tid < H_) coefs[tid] = -log1pf(expf(spc[tid])) * (1.0f/12.0f);
  __syncthreads();
  const float* Rm = R + (size_t)t*9;
  const float r00=Rm[0],r01=Rm[1],r02=Rm[2],r10=Rm[3],r11=Rm[4],r12=Rm[5],r20=Rm[6],r21=Rm[7],r22=Rm[8];
  const float cx = coord[(size_t)t*3], cy = coord[(size_t)t*3+1], cz = coord[(size_t)t*3+2];
  for (int idx = tid; idx < 288; idx += 64) {
    int mat = idx / 96, p = idx % 96;
    const float* s = prow + 1152 + mat*288 + p*3;
    float px=s[0], py=s[1], pz=s[2];
    float gx = r00*px + r01*py + r02*pz + cx;
    float gy = r10*px + r11*py + r12*pz + cy;
    float gz = r20*px + r21*py + r22*pz + cz;
    float* d = (mat==0? qpl : mat==1? kpl : vpl) + p*3;
    d[0]=gx; d[1]=gy; d[2]=gz;
  }
  __syncthreads();
  if (tid < 24) {
    int mat = tid / H_, h = tid % H_;
    const float* s = (mat==0? qpl : kpl) + h*24;
    float acc = 0.f;
    #pragma unroll
    for (int c2 = 0; c2 < 24; ++c2) acc += s[c2]*s[c2];
    (mat==0? qqs : kks)[h] = acc;
  }
  for (int m = tid; m < 72; m += 64)
    ((float4*)(vpg + (size_t)t*288))[m] = ((float4*)vpl)[m];
  __syncthreads();
  for (int idx = tid; idx < 2*H_*64; idx += 64) {
    int which = idx / 768, rem = idx % 768, h = rem >> 6, c = rem & 63;
    float val;
    if (which == 0) {
      if (c < 32)       val = prow[h*32 + c] * ISQD_;
      else if (c < 56)  val = qpl[h*24 + (c-32)] * (-2.0f * coefs[h]);
      else if (c == 56) val = coefs[h] * qqs[h];
      else if (c == 57) val = coefs[h];
      else              val = 0.f;
      qt[((size_t)(n*H_ + h)*L_ + i)*64 + c] = val;
    } else {
      if (c < 32)       val = prow[384 + h*32 + c];
      else if (c < 56)  val = kpl[h*24 + (c-32)];
      else if (c == 56) val = 1.0f;
      else if (c == 57) val = kks[h];
      else              val = 0.f;
      kt[((size_t)(n*H_ + h)*L_ + i)*64 + c] = val;
    }
  }
}

// ---------------------------------------------------------------------------
// K3: logits GEMM: lgal[n][h][i][j] = Qt[i].Kt[j]. 128x64 tile, 8x4 micro.
// ---------------------------------------------------------------------------
__global__ __launch_bounds__(256) void k_lgns(
    const float* __restrict__ qt, const float* __restrict__ kt,
    float* __restrict__ lgal)
{
  const int jb = blockIdx.x * 64, ib = blockIdx.y * 128, nh = blockIdx.z;
  const int tid = threadIdx.x;
  __shared__ float qs[128*66], ks[64*66];
  for (int m = 0; m < 8; ++m) {
    int idx = m*256 + tid;
    int r = idx >> 4, kq = (idx & 15) * 4;
    float4 a = *(const float4*)(qt + ((size_t)nh*L_ + ib + r)*64 + kq);
    qs[r*66+kq]=a.x; qs[r*66+kq+1]=a.y; qs[r*66+kq+2]=a.z; qs[r*66+kq+3]=a.w;
  }
  for (int m = 0; m < 4; ++m) {
    int idx = m*256 + tid;
    int r = idx >> 4, kq = (idx & 15) * 4;
    float4 b = *(const float4*)(kt + ((size_t)nh*L_ + jb + r)*64 + kq);
    ks[r*66+kq]=b.x; ks[r*66+kq+1]=b.y; ks[r*66+kq+2]=b.z; ks[r*66+kq+3]=b.w;
  }
  __syncthreads();
  const int tx = tid & 15, ty = tid >> 4;
  const int i0 = ty*8, j0 = tx*4;
  float acc[8][4] = {};
  #pragma unroll 2
  for (int k2 = 0; k2 < 64; k2 += 2) {
    float2 qv[8], kv[4];
    #pragma unroll
    for (int d = 0; d < 8; ++d) qv[d] = *(const float2*)(qs + (i0+d)*66 + k2);
    #pragma unroll
    for (int e = 0; e < 4; ++e) kv[e] = *(const float2*)(ks + (j0+e)*66 + k2);
    #pragma unroll
    for (int d = 0; d < 8; ++d)
      #pragma unroll
      for (int e = 0; e < 4; ++e)
        acc[d][e] += qv[d].x*kv[e].x + qv[d].y*kv[e].y;
  }
  #pragma unroll
  for (int d = 0; d < 8; ++d) {
    float4 v = make_float4(acc[d][0], acc[d][1], acc[d][2], acc[d][3]);
    *(float4*)(lgal + ((size_t)nh*L_ + ib + i0 + d)*L_ + jb + j0) = v;
  }
}

// ---------------------------------------------------------------------------
// K4: FUSED pair-bias + mask + scale + softmax + feat_pair aggregation.
// r16 structure with ONE change: pt stride 67 -> 68 so phase-1 row reads
// are float4 (16 ds_read_b128 vs 64 ds_read_b32). Wpb stays SCALAR
// (wave-uniform -> s_load; r15 showed float4 Wpb reads become hoisted
// per-lane global loads = 192 VGPRs).
// Bank math for stride 68: addr (68l+4k) dwords -> bank 4*((l+k) mod 8)
// per 16B read; each 8-lane group covers all 32 banks once -> conflict-free.
// ---------------------------------------------------------------------------
__global__ __launch_bounds__(256) void k_pbsa(
    const float* __restrict__ pair, const int* __restrict__ mask,
    const float* __restrict__ Wpb, float* __restrict__ lgal,
    float* __restrict__ feat)
{
  const int i = blockIdx.x, n = blockIdx.y;
  const int bi = n*L_ + i;
  const int tid = threadIdx.x;
  const int l = tid & 63;
  const int w = __builtin_amdgcn_readfirstlane(tid >> 6);
  __shared__ float smem[9312];      // 37.2 KB (pt 2*64*68=8704 | alf+part 9312)
  float* pt0 = smem;
  float* pt1 = smem + 64*68;

  const float* prow = pair + (size_t)bi*L_*PD_;
  const int sr = tid >> 4, scq = (tid & 15)*4;

  // stage tile 0
  #pragma unroll
  for (int m = 0; m < 4; ++m) {
    int r = m*16 + sr;
    float4 v = *(const float4*)(prow + (size_t)r*PD_ + scq);
    *(float4*)(pt0 + r*68 + scq) = v;
  }
  __syncthreads();

  const float* w0 = Wpb + (w    )*64;
  const float* w1 = Wpb + (w + 4)*64;
  const float* w2 = Wpb + (w + 8)*64;
  const int mi = mask[bi];

  const size_t row0 = ((size_t)(n*H_ + w    )*L_ + i)*L_;
  const size_t row1 = ((size_t)(n*H_ + w + 4)*L_ + i)*L_;
  const size_t row2 = ((size_t)(n*H_ + w + 8)*L_ + i)*L_;

  float l0[8], l1[8], l2[8];
  #pragma unroll
  for (int t = 0; t < 8; ++t) {
    float4 rg[4];
    if (t < 7) {
      #pragma unroll
      for (int m = 0; m < 4; ++m) {
        int r = m*16 + sr;
        rg[m] = *(const float4*)(prow + (size_t)((t+1)*64 + r)*PD_ + scq);
      }
    }
    const float* pr = (t & 1 ? pt1 : pt0) + l*68;
    float a0=0.f, a1=0.f, a2=0.f;
    #pragma unroll
    for (int k = 0; k < 16; ++k) {
      float4 pv = *(const float4*)(pr + 4*k);   // ds_read_b128, conflict-free
      // Wpb via SCALAR indexing (wave-uniform -> s_load; keep it scalar!)
      a0 += pv.x*w0[4*k] + pv.y*w0[4*k+1] + pv.z*w0[4*k+2] + pv.w*w0[4*k+3];
      a1 += pv.x*w1[4*k] + pv.y*w1[4*k+1] + pv.z*w1[4*k+2] + pv.w*w1[4*k+3];
      a2 += pv.x*w2[4*k] + pv.y*w2[4*k+1] + pv.z*w2[4*k+2] + pv.w*w2[4*k+3];
    }
    const int j = t*64 + l;
    const float mt = (mi && mask[n*L_ + j]) ? 0.f : -INF_;
    l0[t] = (lgal[row0 + j] + a0)*ISQ3_ + mt;
    l1[t] = (lgal[row1 + j] + a1)*ISQ3_ + mt;
    l2[t] = (lgal[row2 + j] + a2)*ISQ3_ + mt;
    if (t < 7) {
      __syncthreads();
      float* dpt = (t & 1 ? pt0 : pt1);
      #pragma unroll
      for (int m = 0; m < 4; ++m) {
        int r = m*16 + sr;
        *(float4*)(dpt + r*68 + scq) = rg[m];
      }
      __syncthreads();
    }
  }

  // ---- softmax in registers ----
  float mx0=-1e30f, mx1=-1e30f, mx2=-1e30f;
  #pragma unroll
  for (int t = 0; t < 8; ++t) {
    mx0 = fmaxf(mx0, l0[t]); mx1 = fmaxf(mx1, l1[t]); mx2 = fmaxf(mx2, l2[t]);
  }
  #pragma unroll
  for (int off = 1; off < 64; off <<= 1) {
    mx0 = fmaxf(mx0, __shfl_xor(mx0, off, 64));
    mx1 = fmaxf(mx1, __shfl_xor(mx1, off, 64));
    mx2 = fmaxf(mx2, __shfl_xor(mx2, off, 64));
  }
  float s0=0.f, s1=0.f, s2=0.f;
  #pragma unroll
  for (int t = 0; t < 8; ++t) {
    l0[t] = expf(l0[t]-mx0); s0 += l0[t];
    l1[t] = expf(l1[t]-mx1); s1 += l1[t];
    l2[t] = expf(l2[t]-mx2); s2 += l2[t];
  }
  #pragma unroll
  for (int off = 1; off < 64; off <<= 1) {
    s0 += __shfl_xor(s0, off, 64);
    s1 += __shfl_xor(s1, off, 64);
    s2 += __shfl_xor(s2, off, 64);
  }
  const float fm = mi ? 1.f : 0.f;
  s0 = fm/s0; s1 = fm/s1; s2 = fm/s2;

  __syncthreads();                   // all waves done with pt region
  float* alf  = smem;                // 12*520
  float* part = smem + 12*520;       // 4*12*64
  #pragma unroll
  for (int t = 0; t < 8; ++t) {
    const int j = t*64 + l;
    float a0 = l0[t]*s0, a1 = l1[t]*s1, a2 = l2[t]*s2;
    lgal[row0 + j] = a0;  alf[(w    )*520 + j] = a0;
    lgal[row1 + j] = a1;  alf[(w + 4)*520 + j] = a1;
    lgal[row2 + j] = a2;  alf[(w + 8)*520 + j] = a2;
  }
  __syncthreads();

  // ---- phase B: feat_pair aggregation ----
  {
    const int js = l >> 4, cq = (l & 15) << 2;
    float4 acc[H_];
    #pragma unroll
    for (int h = 0; h < H_; ++h) acc[h] = make_float4(0.f,0.f,0.f,0.f);
    for (int g = 0; g < 8; ++g) {
      const int j0 = w*128 + g*16 + js*4;
      float4 pv0 = *(const float4*)(prow + (size_t)(j0  )*PD_ + cq);
      float4 pv1 = *(const float4*)(prow + (size_t)(j0+1)*PD_ + cq);
      float4 pv2 = *(const float4*)(prow + (size_t)(j0+2)*PD_ + cq);
      float4 pv3 = *(const float4*)(prow + (size_t)(j0+3)*PD_ + cq);
      #pragma unroll
      for (int h = 0; h < H_; ++h) {
        float4 a4 = *(const float4*)(alf + h*520 + j0);
        acc[h].x += a4.x*pv0.x + a4.y*pv1.x + a4.z*pv2.x + a4.w*pv3.x;
        acc[h].y += a4.x*pv0.y + a4.y*pv1.y + a4.z*pv2.y + a4.w*pv3.y;
        acc[h].z += a4.x*pv0.z + a4.y*pv1.z + a4.z*pv2.z + a4.w*pv3.z;
        acc[h].w += a4.x*pv0.w + a4.y*pv1.w + a4.z*pv2.w + a4.w*pv3.w;
      }
    }
    #pragma unroll
    for (int h = 0; h < H_; ++h) {
      acc[h].x += __shfl_xor(acc[h].x, 16, 64);
      acc[h].y += __shfl_xor(acc[h].y, 16, 64);
      acc[h].z += __shfl_xor(acc[h].z, 16, 64);
      acc[h].w += __shfl_xor(acc[h].w, 16, 64);
      acc[h].x += __shfl_xor(acc[h].x, 32, 64);
      acc[h].y += __shfl_xor(acc[h].y, 32, 64);
      acc[h].z += __shfl_xor(acc[h].z, 32, 64);
      acc[h].w += __shfl_xor(acc[h].w, 32, 64);
    }
    if (l < 16) {
      #pragma unroll
      for (int h = 0; h < H_; ++h)
        *(float4*)(part + (w*H_ + h)*64 + cq) = acc[h];
    }
    __syncthreads();
    for (int u = tid; u < H_*64; u += 256) {
      int h = u >> 6, c = u & 63;
      feat[(size_t)bi*FEAT_ + h*64 + c] =
          part[(0*H_ + h)*64 + c] + part[(1*H_ + h)*64 + c] +
          part[(2*H_ + h)*64 + c] + part[(3*H_ + h)*64 + c];
    }
  }
}

// ---------------------------------------------------------------------------
// K5: per (n,h,z) GEMM partials over one 64-j tile (z in 0..7):
// pav[z][nh][i][56] = alpha[i, z*64+j] @ [v|vp][j].
// ---------------------------------------------------------------------------
__global__ __launch_bounds__(256) void k_av(
    const float* __restrict__ lgal, const float* __restrict__ proj,
    const float* __restrict__ vpg, float* __restrict__ pav)
{
  const int ib = blockIdx.x * 64;
  const int nh = blockIdx.y;
  const int z  = blockIdx.z;
  const int jb = z*64;
  const int n = nh / H_, h = nh % H_, nL = n*L_;
  const int tid = threadIdx.x;
  __shared__ float as[64*66];
  __shared__ float bs[64*60];
  const int tx = tid & 15, ty = tid >> 4;
  const int i0 = ty*4, c0 = tx*4;
  for (int m = 0; m < 4; ++m) {
    int idx = m*256 + tid;
    int r = idx >> 4, jq = (idx & 15) * 4;
    float4 a = *(const float4*)(lgal + ((size_t)nh*L_ + ib + r)*L_ + jb + jq);
    as[r*66+jq]=a.x; as[r*66+jq+1]=a.y; as[r*66+jq+2]=a.z; as[r*66+jq+3]=a.w;
  }
  for (int m = 0; m < 4; ++m) {
    int idx = m*256 + tid;
    int j = idx >> 4, qq = idx & 15;
    if (qq < 14) {
      float4 v;
      if (qq < 8) v = *(const float4*)(proj + (size_t)(nL + jb + j)*POUT_ + 768 + h*32 + qq*4);
      else        v = *(const float4*)(vpg  + (size_t)(nL + jb + j)*288  + h*24 + (qq-8)*4);
      float* d = bs + j*60 + qq*4;
      d[0]=v.x; d[1]=v.y; d[2]=v.z; d[3]=v.w;
    }
  }
  __syncthreads();
  float acc[4][4] = {};
  #pragma unroll 4
  for (int k2 = 0; k2 < 64; k2 += 2) {
    float2 av[4];
    #pragma unroll
    for (int d = 0; d < 4; ++d) av[d] = *(const float2*)(as + (i0+d)*66 + k2);
    float4 bv0 = *(const float4*)(bs + (k2  )*60 + c0);
    float4 bv1 = *(const float4*)(bs + (k2+1)*60 + c0);
    #pragma unroll
    for (int a2 = 0; a2 < 4; ++a2) {
      acc[a2][0] += av[a2].x*bv0.x + av[a2].y*bv1.x;
      acc[a2][1] += av[a2].x*bv0.y + av[a2].y*bv1.y;
      acc[a2][2] += av[a2].x*bv0.z + av[a2].y*bv1.z;
      acc[a2][3] += av[a2].x*bv0.w + av[a2].y*bv1.w;
    }
  }
  if (c0 < 56) {
    #pragma unroll
    for (int a2 = 0; a2 < 4; ++a2)
      *(float4*)(pav + (((size_t)z*24 + nh)*L_ + ib + i0 + a2)*56 + c0) =
          make_float4(acc[a2][0], acc[a2][1], acc[a2][2], acc[a2][3]);
  }
}

// ---------------------------------------------------------------------------
// K6: reduce 8 k_av partials -> feat_node + fused point post-process
// ---------------------------------------------------------------------------
__global__ __launch_bounds__(256) void k_avred(
    const float* __restrict__ pav, const float* __restrict__ R,
    const float* __restrict__ coord, float* __restrict__ feat)
{
  const int tok = blockIdx.x, tid = threadIdx.x;
  const int n = tok / L_, i = tok % L_;
  __shared__ float ag[288];
  float* fb = feat + (size_t)tok*FEAT_;
  const size_t zstride = (size_t)24*L_*56;
  for (int u = tid; u < 672; u += 256) {
    int h = u / 56, c = u % 56;
    size_t base = (((size_t)(n*H_ + h))*L_ + i)*56 + c;
    float v = 0.f;
    #pragma unroll
    for (int zz = 0; zz < 8; ++zz) v += pav[base + zz*zstride];
    if (c < 32) fb[768 + h*32 + c] = v;
    else        ag[h*24 + (c - 32)] = v;
  }
  __syncthreads();
  if (tid < 96) {
    const float* Rm = R + (size_t)tok*9;
    const float cx = coord[(size_t)tok*3], cy = coord[(size_t)tok*3+1], cz = coord[(size_t)tok*3+2];
    float dx = ag[tid*3] - cx, dy = ag[tid*3+1] - cy, dz = ag[tid*3+2] - cz;
    float fx = Rm[0]*dx + Rm[3]*dy + Rm[6]*dz;
    float fy = Rm[1]*dx + Rm[4]*dy + Rm[7]*dz;
    float fz = Rm[2]*dx + Rm[5]*dy + Rm[8]*dz;
    float dist = sqrtf(fx*fx + fy*fy + fz*fz);
    float idn = 1.f/(dist + 1e-4f);
    fb[1152+tid*3]=fx; fb[1152+tid*3+1]=fy; fb[1152+tid*3+2]=fz;
    fb[1440+tid]=dist;
    fb[1536+tid*3]=fx*idn; fb[1536+tid*3+1]=fy*idn; fb[1536+tid*3+2]=fz*idn;
  }
}

// ---------------------------------------------------------------------------
// K7: y = feat @ Wout^T.  8 tokens x 64 outputs per block.
// ---------------------------------------------------------------------------
__global__ __launch_bounds__(256) void k_y_gemm(
    const float* __restrict__ feat, const float* __restrict__ Wout,
    float* __restrict__ ybuf)
{
  const int rb = blockIdx.x * 8;
  const int ob = blockIdx.y * 64;
  const int tid = threadIdx.x;
  __shared__ float wt[96*65];   // [k][out], padded
  __shared__ float ft[96*10];   // [k][tok], padded
  const int o = tid & 63, tg = tid >> 6;     // tokens tg*2, tg*2+1
  float acc0 = 0.f, acc1 = 0.f;
  for (int kb = 0; kb < FEAT_; kb += 96) {
    for (int m = 0; m < 6; ++m) {
      int idx = m*256 + tid;
      int r = idx / 24, cq = (idx % 24) * 4;
      float4 v = *(const float4*)(Wout + (size_t)(ob + r)*FEAT_ + kb + cq);
      wt[(cq  )*65 + r] = v.x;
      wt[(cq+1)*65 + r] = v.y;
      wt[(cq+2)*65 + r] = v.z;
      wt[(cq+3)*65 + r] = v.w;
    }
    if (tid < 192) {
      int t = tid / 24, cq = (tid % 24) * 4;
      float4 v = *(const float4*)(feat + (size_t)(rb + t)*FEAT_ + kb + cq);
      ft[(cq  )*10 + t] = v.x;
      ft[(cq+1)*10 + t] = v.y;
      ft[(cq+2)*10 + t] = v.z;
      ft[(cq+3)*10 + t] = v.w;
    }
    __syncthreads();
    #pragma unroll 4
    for (int k2 = 0; k2 < 96; ++k2) {
      float wv = wt[k2*65 + o];
      float2 fv = *(const float2*)(ft + k2*10 + tg*2);
      acc0 += wv * fv.x;
      acc1 += wv * fv.y;
    }
    __syncthreads();
  }
  ybuf[(size_t)(rb + tg*2    )*RD_ + ob + o] = acc0;
  ybuf[(size_t)(rb + tg*2 + 1)*RD_ + ob + o] = acc1;
}

// ---------------------------------------------------------------------------
// K8: 4 tokens per block: bias/mask/residual + LN1 + MLP + LN2.
// ---------------------------------------------------------------------------
__global__ __launch_bounds__(256) void k_mlp(
    const float* __restrict__ resf, const int* __restrict__ mask,
    const float* __restrict__ ybuf, const float* __restrict__ bout,
    const float* __restrict__ Wm1, const float* __restrict__ bm1,
    const float* __restrict__ Wm2, const float* __restrict__ bm2,
    const float* __restrict__ Wm3, const float* __restrict__ bm3,
    const float* __restrict__ g1, const float* __restrict__ b1,
    const float* __restrict__ g2, const float* __restrict__ b2,
    float* __restrict__ out)
{
  const int t0 = blockIdx.x*4, tid = threadIdx.x;
  const int tg = tid >> 7, o = tid & 127;
  const int wid = tid >> 6, lane = tid & 63;
  const int ta = t0 + tg*2, tb = ta + 1;
  __shared__ float xb[4][132], hb[4][132];
  __shared__ float reda[4], redb[4];

  float va = ybuf[(size_t)ta*RD_ + o] + bout[o];
  float vb = ybuf[(size_t)tb*RD_ + o] + bout[o];
  if (mask[ta] == 0) va = 0.f;
  if (mask[tb] == 0) vb = 0.f;
  float ra = resf[(size_t)ta*RD_ + o] + va;
  float rb = resf[(size_t)tb*RD_ + o] + vb;

  float pa = ra, pb = rb;
  #pragma unroll
  for (int off = 1; off < 64; off <<= 1) { pa += __shfl_xor(pa, off, 64); pb += __shfl_xor(pb, off, 64); }
  if (lane == 0) { reda[wid] = pa; redb[wid] = pb; }
  __syncthreads();
  float mean_a = (reda[2*tg] + reda[2*tg+1]) * (1.f/RD_);
  float mean_b = (redb[2*tg] + redb[2*tg+1]) * (1.f/RD_);
  __syncthreads();
  float da = ra - mean_a, db = rb - mean_b;
  pa = da*da; pb = db*db;
  #pragma unroll
  for (int off = 1; off < 64; off <<= 1) { pa += __shfl_xor(pa, off, 64); pb += __shfl_xor(pb, off, 64); }
  if (lane == 0) { reda[wid] = pa; redb[wid] = pb; }
  __syncthreads();
  float var_a = (reda[2*tg] + reda[2*tg+1]) * (1.f/RD_);
  float var_b = (redb[2*tg] + redb[2*tg+1]) * (1.f/RD_);
  float xna = da * rsqrtf(var_a + 1e-5f) * g1[o] + b1[o];
  float xnb = db * rsqrtf(var_b + 1e-5f) * g1[o] + b1[o];
  xb[tg*2  ][o] = xna;
  xb[tg*2+1][o] = xnb;
  __syncthreads();

  float a1a = bm1[o], a1b = a1a;
  {
    const float4* w4 = (const float4*)(Wm1 + (size_t)o*RD_);
    #pragma unroll
    for (int c = 0; c < RD_/4; ++c) {
      float4 wv = w4[c];
      float4 xa = *(const float4*)(&xb[tg*2  ][4*c]);
      float4 xv = *(const float4*)(&xb[tg*2+1][4*c]);
      a1a += wv.x*xa.x + wv.y*xa.y + wv.z*xa.z + wv.w*xa.w;
      a1b += wv.x*xv.x + wv.y*xv.y + wv.z*xv.z + wv.w*xv.w;
    }
  }
  a1a = fmaxf(a1a, 0.f); a1b = fmaxf(a1b, 0.f);
  hb[tg*2][o] = a1a; hb[tg*2+1][o] = a1b;
  __syncthreads();

  float a2a = bm2[o], a2b = a2a;
  {
    const float4* w4 = (const float4*)(Wm2 + (size_t)o*RD_);
    #pragma unroll
    for (int c = 0; c < RD_/4; ++c) {
      float4 wv = w4[c];
      float4 xa = *(const float4*)(&hb[tg*2  ][4*c]);
      float4 xv = *(const float4*)(&hb[tg*2+1][4*c]);
      a2a += wv.x*xa.x + wv.y*xa.y + wv.z*xa.z + wv.w*xa.w;
      a2b += wv.x*xv.x + wv.y*xv.y + wv.z*xv.z + wv.w*xv.w;
    }
  }
  a2a = fmaxf(a2a, 0.f); a2b = fmaxf(a2b, 0.f);
  __syncthreads();
  hb[tg*2][o] = a2a; hb[tg*2+1][o] = a2b;
  __syncthreads();

  float a3a = bm3[o], a3b = a3a;
  {
    const float4* w4 = (const float4*)(Wm3 + (size_t)o*RD_);
    #pragma unroll
    for (int c = 0; c < RD_/4; ++c) {
      float4 wv = w4[c];
      float4 xa = *(const float4*)(&hb[tg*2  ][4*c]);
      float4 xv = *(const float4*)(&hb[tg*2+1][4*c]);
      a3a += wv.x*xa.x + wv.y*xa.y + wv.z*xa.z + wv.w*xa.w;
      a3b += wv.x*xv.x + wv.y*xv.y + wv.z*xv.z + wv.w*xv.w;
    }
  }
  float r2a = xna + a3a, r2b = xnb + a3b;

  pa = r2a; pb = r2b;
  #pragma unroll
  for (int off = 1; off < 64; off <<= 1) { pa += __shfl_xor(pa, off, 64); pb += __shfl_xor(pb, off, 64); }
  if (lane == 0) { reda[wid] = pa; redb[wid] = pb; }
  __syncthreads();
  float m2a = (reda[2*tg] + reda[2*tg+1]) * (1.f/RD_);
  float m2b = (redb[2*tg] + redb[2*tg+1]) * (1.f/RD_);
  __syncthreads();
  float d2a = r2a - m2a, d2b = r2b - m2b;
  pa = d2a*d2a; pb = d2b*d2b;
  #pragma unroll
  for (int off = 1; off < 64; off <<= 1) { pa += __shfl_xor(pa, off, 64); pb += __shfl_xor(pb, off, 64); }
  if (lane == 0) { reda[wid] = pa; redb[wid] = pb; }
  __syncthreads();
  float v2a = (reda[2*tg] + reda[2*tg+1]) * (1.f/RD_);
  float v2b = (redb[2*tg] + redb[2*tg+1]) * (1.f/RD_);
  out[(size_t)ta*RD_ + o] = d2a * rsqrtf(v2a + 1e-5f) * g2[o] + b2[o];
  out[(size_t)tb*RD_ + o] = d2b * rsqrtf(v2b + 1e-5f) * g2[o] + b2[o];
}

// ---------------------------------------------------------------------------
extern "C" void kernel_launch(void* const* d_in, const int* in_sizes, int n_in,
                              void* d_out, int out_size, void* d_ws, size_t ws_size,
                              hipStream_t stream) {
  (void)in_sizes; (void)n_in; (void)out_size; (void)ws_size;
  const float* R     = (const float*)d_in[0];
  const float* coord = (const float*)d_in[1];
  const float* resf  = (const float*)d_in[2];
  const float* pair  = (const float*)d_in[3];
  const int*   mask  = (const int*)  d_in[4];
  const float* Wq    = (const float*)d_in[5];
  const float* Wk    = (const float*)d_in[6];
  const float* Wv    = (const float*)d_in[7];
  const float* Wpb   = (const float*)d_in[8];
  const float* spc   = (const float*)d_in[9];
  const float* Wqp   = (const float*)d_in[10];
  const float* Wkp   = (const float*)d_in[11];
  const float* Wvp   = (const float*)d_in[12];
  const float* Wout  = (const float*)d_in[13];
  const float* bout  = (const float*)d_in[14];
  const float* Wm1   = (const float*)d_in[15];
  const float* bm1   = (const float*)d_in[16];
  const float* Wm2   = (const float*)d_in[17];
  const float* bm2   = (const float*)d_in[18];
  const float* Wm3   = (const float*)d_in[19];
  const float* bm3   = (const float*)d_in[20];
  const float* g1    = (const float*)d_in[21];
  const float* b1    = (const float*)d_in[22];
  const float* g2    = (const float*)d_in[23];
  const float* b2    = (const float*)d_in[24];

  float* ws   = (float*)d_ws;
  float* proj = ws;                               // NL*2016
  float* qt   = proj + (size_t)NL_*POUT_;         // 24*512*64
  float* kt   = qt   + (size_t)N_*H_*L_*64;       // 24*512*64
  float* vpg  = kt   + (size_t)N_*H_*L_*64;       // NL*288
  float* lgal = vpg  + (size_t)NL_*288;           // 24*512*512 (logits -> alpha)
  float* feat = lgal + (size_t)N_*H_*L_*L_;       // NL*1824
  float* ybuf = feat + (size_t)NL_*FEAT_;         // NL*128
  float* pav  = ybuf + (size_t)NL_*RD_;           // 8*24*512*56 (22MB)

  k_proj_gemm<<<dim3(NL_/8, 16), 256, 0, stream>>>(resf, Wq, Wk, Wv, Wqp, Wkp, Wvp, proj);
  k_rot<<<NL_, 64, 0, stream>>>(R, coord, spc, proj, qt, kt, vpg);
  k_lgns<<<dim3(L_/64, L_/128, N_*H_), 256, 0, stream>>>(qt, kt, lgal);
  k_pbsa<<<dim3(L_, N_), 256, 0, stream>>>(pair, mask, Wpb, lgal, feat);
  k_av<<<dim3(L_/64, N_*H_, 8), 256, 0, stream>>>(lgal, proj, vpg, pav);
  k_avred<<<NL_, 256, 0, stream>>>(pav, R, coord, feat);
  k_y_gemm<<<dim3(NL_/8, 2), 256, 0, stream>>>(feat, Wout, ybuf);
  k_mlp<<<NL_/4, 256, 0, stream>>>(resf, mask, ybuf, bout, Wm1, bm1, Wm2, bm2, Wm3, bm3,
                                   g1, b1, g2, b2, (float*)d_out);
}

// Round 19
// 211.593 us; speedup vs baseline: 2.0404x; 2.0404x over previous
//
#include <hip/hip_runtime.h>
#include <hip/hip_bf16.h>

#define N_ 2
#define L_ 512
#define RD_ 128
#define PD_ 64
#define H_ 12
#define NL_ (N_*L_)
#define POUT_ 2016          /* 3*384 + 3*288 */
#define FEAT_ 1824
#define INF_ 100000.0f
#define ISQD_ 0.17677669529663687f   /* 1/sqrt(32) */
#define ISQ3_ 0.5773502691896258f    /* sqrt(1/3) */
#define LL_ ((size_t)L_*L_)

// ---------------------------------------------------------------------------
// K1: projection GEMM. proj[token][2016] = resf @ [Wq|Wk|Wv|Wqp|Wkp|Wvp]^T
// ---------------------------------------------------------------------------
__global__ __launch_bounds__(256) void k_proj_gemm(
    const float* __restrict__ resf,
    const float* __restrict__ Wq, const float* __restrict__ Wk, const float* __restrict__ Wv,
    const float* __restrict__ Wqp, const float* __restrict__ Wkp, const float* __restrict__ Wvp,
    float* __restrict__ proj)
{
  const int rb = blockIdx.x * 8;
  const int ob = blockIdx.y * 128;
  const int tid = threadIdx.x;
  __shared__ float xt[8*132];
  __shared__ float wt[128*132];
  {
    int r = tid >> 5, kq = (tid & 31) * 4;
    float4 v = *(const float4*)(resf + (size_t)(rb + r)*RD_ + kq);
    xt[r*132+kq]=v.x; xt[r*132+kq+1]=v.y; xt[r*132+kq+2]=v.z; xt[r*132+kq+3]=v.w;
  }
  for (int m = 0; m < 16; ++m) {
    int idx = m*256 + tid;
    int r = idx >> 5, kq = (idx & 31) * 4;
    int o = ob + r;
    float4 v;
    if (o < 384)        v = *(const float4*)(Wq  + (size_t)o*RD_ + kq);
    else if (o < 768)   v = *(const float4*)(Wk  + (size_t)(o-384)*RD_ + kq);
    else if (o < 1152)  v = *(const float4*)(Wv  + (size_t)(o-768)*RD_ + kq);
    else if (o < 1440)  v = *(const float4*)(Wqp + (size_t)(o-1152)*RD_ + kq);
    else if (o < 1728)  v = *(const float4*)(Wkp + (size_t)(o-1440)*RD_ + kq);
    else if (o < POUT_) v = *(const float4*)(Wvp + (size_t)(o-1728)*RD_ + kq);
    else                v = make_float4(0.f,0.f,0.f,0.f);
    wt[r*132+kq]=v.x; wt[r*132+kq+1]=v.y; wt[r*132+kq+2]=v.z; wt[r*132+kq+3]=v.w;
  }
  __syncthreads();
  const int tt = tid & 7, g = tid >> 3;
  float acc0=0.f, acc1=0.f, acc2=0.f, acc3=0.f;
  #pragma unroll 4
  for (int k2 = 0; k2 < RD_; k2 += 2) {
    float2 xv = *(const float2*)(xt + tt*132 + k2);
    float2 w0 = *(const float2*)(wt + (g     )*132 + k2);
    float2 w1 = *(const float2*)(wt + (g + 32)*132 + k2);
    float2 w2 = *(const float2*)(wt + (g + 64)*132 + k2);
    float2 w3 = *(const float2*)(wt + (g + 96)*132 + k2);
    acc0 += xv.x*w0.x + xv.y*w0.y;
    acc1 += xv.x*w1.x + xv.y*w1.y;
    acc2 += xv.x*w2.x + xv.y*w2.y;
    acc3 += xv.x*w3.x + xv.y*w3.y;
  }
  float* dst = proj + (size_t)(rb + tt)*POUT_ + ob;
  if (ob + g      < POUT_) dst[g]      = acc0;
  if (ob + g + 32 < POUT_) dst[g+32]   = acc1;
  if (ob + g + 64 < POUT_) dst[g+64]   = acc2;
  if (ob + g + 96 < POUT_) dst[g+96]   = acc3;
}

// ---------------------------------------------------------------------------
// K2: per-token rotate + build Q~/K~ (58-dim augmented, padded to 64)
// ---------------------------------------------------------------------------
__global__ __launch_bounds__(64) void k_rot(
    const float* __restrict__ R, const float* __restrict__ coord,
    const float* __restrict__ spc, const float* __restrict__ proj,
    float* __restrict__ qt, float* __restrict__ kt, float* __restrict__ vpg)
{
  const int t = blockIdx.x;
  const int n = t / L_, i = t % L_;
  const int tid = threadIdx.x;
  __shared__ float prow[POUT_];
  __shared__ float qpl[288], kpl[288], vpl[288];
  __shared__ float qqs[H_], kks[H_], coefs[H_];
  for (int m = tid; m < POUT_/4; m += 64)
    ((float4*)prow)[m] = *((const float4*)(proj + (size_t)t*POUT_) + m);
  if (tid < H_) coefs[tid] = -log1pf(expf(spc[tid])) * (1.0f/12.0f);
  __syncthreads();
  const float* Rm = R + (size_t)t*9;
  const float r00=Rm[0],r01=Rm[1],r02=Rm[2],r10=Rm[3],r11=Rm[4],r12=Rm[5],r20=Rm[6],r21=Rm[7],r22=Rm[8];
  const float cx = coord[(size_t)t*3], cy = coord[(size_t)t*3+1], cz = coord[(size_t)t*3+2];
  for (int idx = tid; idx < 288; idx += 64) {
    int mat = idx / 96, p = idx % 96;
    const float* s = prow + 1152 + mat*288 + p*3;
    float px=s[0], py=s[1], pz=s[2];
    float gx = r00*px + r01*py + r02*pz + cx;
    float gy = r10*px + r11*py + r12*pz + cy;
    float gz = r20*px + r21*py + r22*pz + cz;
    float* d = (mat==0? qpl : mat==1? kpl : vpl) + p*3;
    d[0]=gx; d[1]=gy; d[2]=gz;
  }
  __syncthreads();
  if (tid < 24) {
    int mat = tid / H_, h = tid % H_;
    const float* s = (mat==0? qpl : kpl) + h*24;
    float acc = 0.f;
    #pragma unroll
    for (int c2 = 0; c2 < 24; ++c2) acc += s[c2]*s[c2];
    (mat==0? qqs : kks)[h] = acc;
  }
  for (int m = tid; m < 72; m += 64)
    ((float4*)(vpg + (size_t)t*288))[m] = ((float4*)vpl)[m];
  __syncthreads();
  for (int idx = tid; idx < 2*H_*64; idx += 64) {
    int which = idx / 768, rem = idx % 768, h = rem >> 6, c = rem & 63;
    float val;
    if (which == 0) {
      if (c < 32)       val = prow[h*32 + c] * ISQD_;
      else if (c < 56)  val = qpl[h*24 + (c-32)] * (-2.0f * coefs[h]);
      else if (c == 56) val = coefs[h] * qqs[h];
      else if (c == 57) val = coefs[h];
      else              val = 0.f;
      qt[((size_t)(n*H_ + h)*L_ + i)*64 + c] = val;
    } else {
      if (c < 32)       val = prow[384 + h*32 + c];
      else if (c < 56)  val = kpl[h*24 + (c-32)];
      else if (c == 56) val = 1.0f;
      else if (c == 57) val = kks[h];
      else              val = 0.f;
      kt[((size_t)(n*H_ + h)*L_ + i)*64 + c] = val;
    }
  }
}

// ---------------------------------------------------------------------------
// K3: logits GEMM: lgal[n][h][i][j] = Qt[i].Kt[j]. 128x64 tile, 8x4 micro.
// ---------------------------------------------------------------------------
__global__ __launch_bounds__(256) void k_lgns(
    const float* __restrict__ qt, const float* __restrict__ kt,
    float* __restrict__ lgal)
{
  const int jb = blockIdx.x * 64, ib = blockIdx.y * 128, nh = blockIdx.z;
  const int tid = threadIdx.x;
  __shared__ float qs[128*66], ks[64*66];
  for (int m = 0; m < 8; ++m) {
    int idx = m*256 + tid;
    int r = idx >> 4, kq = (idx & 15) * 4;
    float4 a = *(const float4*)(qt + ((size_t)nh*L_ + ib + r)*64 + kq);
    qs[r*66+kq]=a.x; qs[r*66+kq+1]=a.y; qs[r*66+kq+2]=a.z; qs[r*66+kq+3]=a.w;
  }
  for (int m = 0; m < 4; ++m) {
    int idx = m*256 + tid;
    int r = idx >> 4, kq = (idx & 15) * 4;
    float4 b = *(const float4*)(kt + ((size_t)nh*L_ + jb + r)*64 + kq);
    ks[r*66+kq]=b.x; ks[r*66+kq+1]=b.y; ks[r*66+kq+2]=b.z; ks[r*66+kq+3]=b.w;
  }
  __syncthreads();
  const int tx = tid & 15, ty = tid >> 4;
  const int i0 = ty*8, j0 = tx*4;
  float acc[8][4] = {};
  #pragma unroll 2
  for (int k2 = 0; k2 < 64; k2 += 2) {
    float2 qv[8], kv[4];
    #pragma unroll
    for (int d = 0; d < 8; ++d) qv[d] = *(const float2*)(qs + (i0+d)*66 + k2);
    #pragma unroll
    for (int e = 0; e < 4; ++e) kv[e] = *(const float2*)(ks + (j0+e)*66 + k2);
    #pragma unroll
    for (int d = 0; d < 8; ++d)
      #pragma unroll
      for (int e = 0; e < 4; ++e)
        acc[d][e] += qv[d].x*kv[e].x + qv[d].y*kv[e].y;
  }
  #pragma unroll
  for (int d = 0; d < 8; ++d) {
    float4 v = make_float4(acc[d][0], acc[d][1], acc[d][2], acc[d][3]);
    *(float4*)(lgal + ((size_t)nh*L_ + ib + i0 + d)*L_ + jb + j0) = v;
  }
}

// ---------------------------------------------------------------------------
// K4: FUSED pair-bias + mask + scale + softmax + feat_pair aggregation.
// r14/r16-VERIFIED version (VGPR 52, 79 us, total 212 us): stride-67 pt
// tiles with SCALAR b32 LDS reads and SCALAR Wpb reads. Do NOT widen any
// phase-1 read: both float4 variants (r15: Wpb float4; r17: LDS float4)
// trigger a register-hoist storm to VGPR 256 and a ~3.6x kernel slowdown.
// ---------------------------------------------------------------------------
__global__ __launch_bounds__(256) void k_pbsa(
    const float* __restrict__ pair, const int* __restrict__ mask,
    const float* __restrict__ Wpb, float* __restrict__ lgal,
    float* __restrict__ feat)
{
  const int i = blockIdx.x, n = blockIdx.y;
  const int bi = n*L_ + i;
  const int tid = threadIdx.x;
  const int l = tid & 63;
  const int w = __builtin_amdgcn_readfirstlane(tid >> 6);
  __shared__ float smem[9312];      // 37.2 KB
  float* pt0 = smem;                // 64*67
  float* pt1 = smem + 64*67;

  const float* prow = pair + (size_t)bi*L_*PD_;
  const int sr = tid >> 4, scq = (tid & 15)*4;

  // stage tile 0
  #pragma unroll
  for (int m = 0; m < 4; ++m) {
    int r = m*16 + sr;
    float4 v = *(const float4*)(prow + (size_t)r*PD_ + scq);
    float* d = pt0 + r*67 + scq;
    d[0]=v.x; d[1]=v.y; d[2]=v.z; d[3]=v.w;
  }
  __syncthreads();

  const float* w0 = Wpb + (w    )*64;
  const float* w1 = Wpb + (w + 4)*64;
  const float* w2 = Wpb + (w + 8)*64;
  const int mi = mask[bi];

  const size_t row0 = ((size_t)(n*H_ + w    )*L_ + i)*L_;
  const size_t row1 = ((size_t)(n*H_ + w + 4)*L_ + i)*L_;
  const size_t row2 = ((size_t)(n*H_ + w + 8)*L_ + i)*L_;

  float l0[8], l1[8], l2[8];
  #pragma unroll
  for (int t = 0; t < 8; ++t) {
    float4 rg[4];
    if (t < 7) {
      #pragma unroll
      for (int m = 0; m < 4; ++m) {
        int r = m*16 + sr;
        rg[m] = *(const float4*)(prow + (size_t)((t+1)*64 + r)*PD_ + scq);
      }
    }
    const float* pr = (t & 1 ? pt1 : pt0) + l*67;
    float a0=0.f, a1=0.f, a2=0.f;
    #pragma unroll 16
    for (int c = 0; c < 64; ++c) {
      float pv = pr[c];
      a0 += pv*w0[c]; a1 += pv*w1[c]; a2 += pv*w2[c];
    }
    const int j = t*64 + l;
    const float mt = (mi && mask[n*L_ + j]) ? 0.f : -INF_;
    l0[t] = (lgal[row0 + j] + a0)*ISQ3_ + mt;
    l1[t] = (lgal[row1 + j] + a1)*ISQ3_ + mt;
    l2[t] = (lgal[row2 + j] + a2)*ISQ3_ + mt;
    if (t < 7) {
      __syncthreads();
      float* dpt = (t & 1 ? pt0 : pt1);
      #pragma unroll
      for (int m = 0; m < 4; ++m) {
        int r = m*16 + sr;
        float* d = dpt + r*67 + scq;
        d[0]=rg[m].x; d[1]=rg[m].y; d[2]=rg[m].z; d[3]=rg[m].w;
      }
      __syncthreads();
    }
  }

  // ---- softmax in registers ----
  float mx0=-1e30f, mx1=-1e30f, mx2=-1e30f;
  #pragma unroll
  for (int t = 0; t < 8; ++t) {
    mx0 = fmaxf(mx0, l0[t]); mx1 = fmaxf(mx1, l1[t]); mx2 = fmaxf(mx2, l2[t]);
  }
  #pragma unroll
  for (int off = 1; off < 64; off <<= 1) {
    mx0 = fmaxf(mx0, __shfl_xor(mx0, off, 64));
    mx1 = fmaxf(mx1, __shfl_xor(mx1, off, 64));
    mx2 = fmaxf(mx2, __shfl_xor(mx2, off, 64));
  }
  float s0=0.f, s1=0.f, s2=0.f;
  #pragma unroll
  for (int t = 0; t < 8; ++t) {
    l0[t] = expf(l0[t]-mx0); s0 += l0[t];
    l1[t] = expf(l1[t]-mx1); s1 += l1[t];
    l2[t] = expf(l2[t]-mx2); s2 += l2[t];
  }
  #pragma unroll
  for (int off = 1; off < 64; off <<= 1) {
    s0 += __shfl_xor(s0, off, 64);
    s1 += __shfl_xor(s1, off, 64);
    s2 += __shfl_xor(s2, off, 64);
  }
  const float fm = mi ? 1.f : 0.f;
  s0 = fm/s0; s1 = fm/s1; s2 = fm/s2;

  __syncthreads();                   // all waves done with pt region
  float* alf  = smem;                // 12*520
  float* part = smem + 12*520;       // 4*12*64
  #pragma unroll
  for (int t = 0; t < 8; ++t) {
    const int j = t*64 + l;
    float a0 = l0[t]*s0, a1 = l1[t]*s1, a2 = l2[t]*s2;
    lgal[row0 + j] = a0;  alf[(w    )*520 + j] = a0;
    lgal[row1 + j] = a1;  alf[(w + 4)*520 + j] = a1;
    lgal[row2 + j] = a2;  alf[(w + 8)*520 + j] = a2;
  }
  __syncthreads();

  // ---- phase B: feat_pair aggregation ----
  {
    const int js = l >> 4, cq = (l & 15) << 2;
    float4 acc[H_];
    #pragma unroll
    for (int h = 0; h < H_; ++h) acc[h] = make_float4(0.f,0.f,0.f,0.f);
    for (int g = 0; g < 8; ++g) {
      const int j0 = w*128 + g*16 + js*4;
      float4 pv0 = *(const float4*)(prow + (size_t)(j0  )*PD_ + cq);
      float4 pv1 = *(const float4*)(prow + (size_t)(j0+1)*PD_ + cq);
      float4 pv2 = *(const float4*)(prow + (size_t)(j0+2)*PD_ + cq);
      float4 pv3 = *(const float4*)(prow + (size_t)(j0+3)*PD_ + cq);
      #pragma unroll
      for (int h = 0; h < H_; ++h) {
        float4 a4 = *(const float4*)(alf + h*520 + j0);
        acc[h].x += a4.x*pv0.x + a4.y*pv1.x + a4.z*pv2.x + a4.w*pv3.x;
        acc[h].y += a4.x*pv0.y + a4.y*pv1.y + a4.z*pv2.y + a4.w*pv3.y;
        acc[h].z += a4.x*pv0.z + a4.y*pv1.z + a4.z*pv2.z + a4.w*pv3.z;
        acc[h].w += a4.x*pv0.w + a4.y*pv1.w + a4.z*pv2.w + a4.w*pv3.w;
      }
    }
    #pragma unroll
    for (int h = 0; h < H_; ++h) {
      acc[h].x += __shfl_xor(acc[h].x, 16, 64);
      acc[h].y += __shfl_xor(acc[h].y, 16, 64);
      acc[h].z += __shfl_xor(acc[h].z, 16, 64);
      acc[h].w += __shfl_xor(acc[h].w, 16, 64);
      acc[h].x += __shfl_xor(acc[h].x, 32, 64);
      acc[h].y += __shfl_xor(acc[h].y, 32, 64);
      acc[h].z += __shfl_xor(acc[h].z, 32, 64);
      acc[h].w += __shfl_xor(acc[h].w, 32, 64);
    }
    if (l < 16) {
      #pragma unroll
      for (int h = 0; h < H_; ++h)
        *(float4*)(part + (w*H_ + h)*64 + cq) = acc[h];
    }
    __syncthreads();
    for (int u = tid; u < H_*64; u += 256) {
      int h = u >> 6, c = u & 63;
      feat[(size_t)bi*FEAT_ + h*64 + c] =
          part[(0*H_ + h)*64 + c] + part[(1*H_ + h)*64 + c] +
          part[(2*H_ + h)*64 + c] + part[(3*H_ + h)*64 + c];
    }
  }
}

// ---------------------------------------------------------------------------
// K5: per (n,h,z) GEMM partials over one 64-j tile (z in 0..7):
// pav[z][nh][i][56] = alpha[i, z*64+j] @ [v|vp][j].
// ---------------------------------------------------------------------------
__global__ __launch_bounds__(256) void k_av(
    const float* __restrict__ lgal, const float* __restrict__ proj,
    const float* __restrict__ vpg, float* __restrict__ pav)
{
  const int ib = blockIdx.x * 64;
  const int nh = blockIdx.y;
  const int z  = blockIdx.z;
  const int jb = z*64;
  const int n = nh / H_, h = nh % H_, nL = n*L_;
  const int tid = threadIdx.x;
  __shared__ float as[64*66];
  __shared__ float bs[64*60];
  const int tx = tid & 15, ty = tid >> 4;
  const int i0 = ty*4, c0 = tx*4;
  for (int m = 0; m < 4; ++m) {
    int idx = m*256 + tid;
    int r = idx >> 4, jq = (idx & 15) * 4;
    float4 a = *(const float4*)(lgal + ((size_t)nh*L_ + ib + r)*L_ + jb + jq);
    as[r*66+jq]=a.x; as[r*66+jq+1]=a.y; as[r*66+jq+2]=a.z; as[r*66+jq+3]=a.w;
  }
  for (int m = 0; m < 4; ++m) {
    int idx = m*256 + tid;
    int j = idx >> 4, qq = idx & 15;
    if (qq < 14) {
      float4 v;
      if (qq < 8) v = *(const float4*)(proj + (size_t)(nL + jb + j)*POUT_ + 768 + h*32 + qq*4);
      else        v = *(const float4*)(vpg  + (size_t)(nL + jb + j)*288  + h*24 + (qq-8)*4);
      float* d = bs + j*60 + qq*4;
      d[0]=v.x; d[1]=v.y; d[2]=v.z; d[3]=v.w;
    }
  }
  __syncthreads();
  float acc[4][4] = {};
  #pragma unroll 4
  for (int k2 = 0; k2 < 64; k2 += 2) {
    float2 av[4];
    #pragma unroll
    for (int d = 0; d < 4; ++d) av[d] = *(const float2*)(as + (i0+d)*66 + k2);
    float4 bv0 = *(const float4*)(bs + (k2  )*60 + c0);
    float4 bv1 = *(const float4*)(bs + (k2+1)*60 + c0);
    #pragma unroll
    for (int a2 = 0; a2 < 4; ++a2) {
      acc[a2][0] += av[a2].x*bv0.x + av[a2].y*bv1.x;
      acc[a2][1] += av[a2].x*bv0.y + av[a2].y*bv1.y;
      acc[a2][2] += av[a2].x*bv0.z + av[a2].y*bv1.z;
      acc[a2][3] += av[a2].x*bv0.w + av[a2].y*bv1.w;
    }
  }
  if (c0 < 56) {
    #pragma unroll
    for (int a2 = 0; a2 < 4; ++a2)
      *(float4*)(pav + (((size_t)z*24 + nh)*L_ + ib + i0 + a2)*56 + c0) =
          make_float4(acc[a2][0], acc[a2][1], acc[a2][2], acc[a2][3]);
  }
}

// ---------------------------------------------------------------------------
// K6: reduce 8 k_av partials -> feat_node + fused point post-process
// ---------------------------------------------------------------------------
__global__ __launch_bounds__(256) void k_avred(
    const float* __restrict__ pav, const float* __restrict__ R,
    const float* __restrict__ coord, float* __restrict__ feat)
{
  const int tok = blockIdx.x, tid = threadIdx.x;
  const int n = tok / L_, i = tok % L_;
  __shared__ float ag[288];
  float* fb = feat + (size_t)tok*FEAT_;
  const size_t zstride = (size_t)24*L_*56;
  for (int u = tid; u < 672; u += 256) {
    int h = u / 56, c = u % 56;
    size_t base = (((size_t)(n*H_ + h))*L_ + i)*56 + c;
    float v = 0.f;
    #pragma unroll
    for (int zz = 0; zz < 8; ++zz) v += pav[base + zz*zstride];
    if (c < 32) fb[768 + h*32 + c] = v;
    else        ag[h*24 + (c - 32)] = v;
  }
  __syncthreads();
  if (tid < 96) {
    const float* Rm = R + (size_t)tok*9;
    const float cx = coord[(size_t)tok*3], cy = coord[(size_t)tok*3+1], cz = coord[(size_t)tok*3+2];
    float dx = ag[tid*3] - cx, dy = ag[tid*3+1] - cy, dz = ag[tid*3+2] - cz;
    float fx = Rm[0]*dx + Rm[3]*dy + Rm[6]*dz;
    float fy = Rm[1]*dx + Rm[4]*dy + Rm[7]*dz;
    float fz = Rm[2]*dx + Rm[5]*dy + Rm[8]*dz;
    float dist = sqrtf(fx*fx + fy*fy + fz*fz);
    float idn = 1.f/(dist + 1e-4f);
    fb[1152+tid*3]=fx; fb[1152+tid*3+1]=fy; fb[1152+tid*3+2]=fz;
    fb[1440+tid]=dist;
    fb[1536+tid*3]=fx*idn; fb[1536+tid*3+1]=fy*idn; fb[1536+tid*3+2]=fz*idn;
  }
}

// ---------------------------------------------------------------------------
// K7: y = feat @ Wout^T.  8 tokens x 64 outputs per block.
// ---------------------------------------------------------------------------
__global__ __launch_bounds__(256) void k_y_gemm(
    const float* __restrict__ feat, const float* __restrict__ Wout,
    float* __restrict__ ybuf)
{
  const int rb = blockIdx.x * 8;
  const int ob = blockIdx.y * 64;
  const int tid = threadIdx.x;
  __shared__ float wt[96*65];   // [k][out], padded
  __shared__ float ft[96*10];   // [k][tok], padded
  const int o = tid & 63, tg = tid >> 6;     // tokens tg*2, tg*2+1
  float acc0 = 0.f, acc1 = 0.f;
  for (int kb = 0; kb < FEAT_; kb += 96) {
    for (int m = 0; m < 6; ++m) {
      int idx = m*256 + tid;
      int r = idx / 24, cq = (idx % 24) * 4;
      float4 v = *(const float4*)(Wout + (size_t)(ob + r)*FEAT_ + kb + cq);
      wt[(cq  )*65 + r] = v.x;
      wt[(cq+1)*65 + r] = v.y;
      wt[(cq+2)*65 + r] = v.z;
      wt[(cq+3)*65 + r] = v.w;
    }
    if (tid < 192) {
      int t = tid / 24, cq = (tid % 24) * 4;
      float4 v = *(const float4*)(feat + (size_t)(rb + t)*FEAT_ + kb + cq);
      ft[(cq  )*10 + t] = v.x;
      ft[(cq+1)*10 + t] = v.y;
      ft[(cq+2)*10 + t] = v.z;
      ft[(cq+3)*10 + t] = v.w;
    }
    __syncthreads();
    #pragma unroll 4
    for (int k2 = 0; k2 < 96; ++k2) {
      float wv = wt[k2*65 + o];
      float2 fv = *(const float2*)(ft + k2*10 + tg*2);
      acc0 += wv * fv.x;
      acc1 += wv * fv.y;
    }
    __syncthreads();
  }
  ybuf[(size_t)(rb + tg*2    )*RD_ + ob + o] = acc0;
  ybuf[(size_t)(rb + tg*2 + 1)*RD_ + ob + o] = acc1;
}

// ---------------------------------------------------------------------------
// K8: 4 tokens per block: bias/mask/residual + LN1 + MLP + LN2.
// ---------------------------------------------------------------------------
__global__ __launch_bounds__(256) void k_mlp(
    const float* __restrict__ resf, const int* __restrict__ mask,
    const float* __restrict__ ybuf, const float* __restrict__ bout,
    const float* __restrict__ Wm1, const float* __restrict__ bm1,
    const float* __restrict__ Wm2, const float* __restrict__ bm2,
    const float* __restrict__ Wm3, const float* __restrict__ bm3,
    const float* __restrict__ g1, const float* __restrict__ b1,
    const float* __restrict__ g2, const float* __restrict__ b2,
    float* __restrict__ out)
{
  const int t0 = blockIdx.x*4, tid = threadIdx.x;
  const int tg = tid >> 7, o = tid & 127;
  const int wid = tid >> 6, lane = tid & 63;
  const int ta = t0 + tg*2, tb = ta + 1;
  __shared__ float xb[4][132], hb[4][132];
  __shared__ float reda[4], redb[4];

  float va = ybuf[(size_t)ta*RD_ + o] + bout[o];
  float vb = ybuf[(size_t)tb*RD_ + o] + bout[o];
  if (mask[ta] == 0) va = 0.f;
  if (mask[tb] == 0) vb = 0.f;
  float ra = resf[(size_t)ta*RD_ + o] + va;
  float rb = resf[(size_t)tb*RD_ + o] + vb;

  float pa = ra, pb = rb;
  #pragma unroll
  for (int off = 1; off < 64; off <<= 1) { pa += __shfl_xor(pa, off, 64); pb += __shfl_xor(pb, off, 64); }
  if (lane == 0) { reda[wid] = pa; redb[wid] = pb; }
  __syncthreads();
  float mean_a = (reda[2*tg] + reda[2*tg+1]) * (1.f/RD_);
  float mean_b = (redb[2*tg] + redb[2*tg+1]) * (1.f/RD_);
  __syncthreads();
  float da = ra - mean_a, db = rb - mean_b;
  pa = da*da; pb = db*db;
  #pragma unroll
  for (int off = 1; off < 64; off <<= 1) { pa += __shfl_xor(pa, off, 64); pb += __shfl_xor(pb, off, 64); }
  if (lane == 0) { reda[wid] = pa; redb[wid] = pb; }
  __syncthreads();
  float var_a = (reda[2*tg] + reda[2*tg+1]) * (1.f/RD_);
  float var_b = (redb[2*tg] + redb[2*tg+1]) * (1.f/RD_);
  float xna = da * rsqrtf(var_a + 1e-5f) * g1[o] + b1[o];
  float xnb = db * rsqrtf(var_b + 1e-5f) * g1[o] + b1[o];
  xb[tg*2  ][o] = xna;
  xb[tg*2+1][o] = xnb;
  __syncthreads();

  float a1a = bm1[o], a1b = a1a;
  {
    const float4* w4 = (const float4*)(Wm1 + (size_t)o*RD_);
    #pragma unroll
    for (int c = 0; c < RD_/4; ++c) {
      float4 wv = w4[c];
      float4 xa = *(const float4*)(&xb[tg*2  ][4*c]);
      float4 xv = *(const float4*)(&xb[tg*2+1][4*c]);
      a1a += wv.x*xa.x + wv.y*xa.y + wv.z*xa.z + wv.w*xa.w;
      a1b += wv.x*xv.x + wv.y*xv.y + wv.z*xv.z + wv.w*xv.w;
    }
  }
  a1a = fmaxf(a1a, 0.f); a1b = fmaxf(a1b, 0.f);
  hb[tg*2][o] = a1a; hb[tg*2+1][o] = a1b;
  __syncthreads();

  float a2a = bm2[o], a2b = a2a;
  {
    const float4* w4 = (const float4*)(Wm2 + (size_t)o*RD_);
    #pragma unroll
    for (int c = 0; c < RD_/4; ++c) {
      float4 wv = w4[c];
      float4 xa = *(const float4*)(&hb[tg*2  ][4*c]);
      float4 xv = *(const float4*)(&hb[tg*2+1][4*c]);
      a2a += wv.x*xa.x + wv.y*xa.y + wv.z*xa.z + wv.w*xa.w;
      a2b += wv.x*xv.x + wv.y*xv.y + wv.z*xv.z + wv.w*xv.w;
    }
  }
  a2a = fmaxf(a2a, 0.f); a2b = fmaxf(a2b, 0.f);
  __syncthreads();
  hb[tg*2][o] = a2a; hb[tg*2+1][o] = a2b;
  __syncthreads();

  float a3a = bm3[o], a3b = a3a;
  {
    const float4* w4 = (const float4*)(Wm3 + (size_t)o*RD_);
    #pragma unroll
    for (int c = 0; c < RD_/4; ++c) {
      float4 wv = w4[c];
      float4 xa = *(const float4*)(&hb[tg*2  ][4*c]);
      float4 xv = *(const float4*)(&hb[tg*2+1][4*c]);
      a3a += wv.x*xa.x + wv.y*xa.y + wv.z*xa.z + wv.w*xa.w;
      a3b += wv.x*xv.x + wv.y*xv.y + wv.z*xv.z + wv.w*xv.w;
    }
  }
  float r2a = xna + a3a, r2b = xnb + a3b;

  pa = r2a; pb = r2b;
  #pragma unroll
  for (int off = 1; off < 64; off <<= 1) { pa += __shfl_xor(pa, off, 64); pb += __shfl_xor(pb, off, 64); }
  if (lane == 0) { reda[wid] = pa; redb[wid] = pb; }
  __syncthreads();
  float m2a = (reda[2*tg] + reda[2*tg+1]) * (1.f/RD_);
  float m2b = (redb[2*tg] + redb[2*tg+1]) * (1.f/RD_);
  __syncthreads();
  float d2a = r2a - m2a, d2b = r2b - m2b;
  pa = d2a*d2a; pb = d2b*d2b;
  #pragma unroll
  for (int off = 1; off < 64; off <<= 1) { pa += __shfl_xor(pa, off, 64); pb += __shfl_xor(pb, off, 64); }
  if (lane == 0) { reda[wid] = pa; redb[wid] = pb; }
  __syncthreads();
  float v2a = (reda[2*tg] + reda[2*tg+1]) * (1.f/RD_);
  float v2b = (redb[2*tg] + redb[2*tg+1]) * (1.f/RD_);
  out[(size_t)ta*RD_ + o] = d2a * rsqrtf(v2a + 1e-5f) * g2[o] + b2[o];
  out[(size_t)tb*RD_ + o] = d2b * rsqrtf(v2b + 1e-5f) * g2[o] + b2[o];
}

// ---------------------------------------------------------------------------
extern "C" void kernel_launch(void* const* d_in, const int* in_sizes, int n_in,
                              void* d_out, int out_size, void* d_ws, size_t ws_size,
                              hipStream_t stream) {
  (void)in_sizes; (void)n_in; (void)out_size; (void)ws_size;
  const float* R     = (const float*)d_in[0];
  const float* coord = (const float*)d_in[1];
  const float* resf  = (const float*)d_in[2];
  const float* pair  = (const float*)d_in[3];
  const int*   mask  = (const int*)  d_in[4];
  const float* Wq    = (const float*)d_in[5];
  const float* Wk    = (const float*)d_in[6];
  const float* Wv    = (const float*)d_in[7];
  const float* Wpb   = (const float*)d_in[8];
  const float* spc   = (const float*)d_in[9];
  const float* Wqp   = (const float*)d_in[10];
  const float* Wkp   = (const float*)d_in[11];
  const float* Wvp   = (const float*)d_in[12];
  const float* Wout  = (const float*)d_in[13];
  const float* bout  = (const float*)d_in[14];
  const float* Wm1   = (const float*)d_in[15];
  const float* bm1   = (const float*)d_in[16];
  const float* Wm2   = (const float*)d_in[17];
  const float* bm2   = (const float*)d_in[18];
  const float* Wm3   = (const float*)d_in[19];
  const float* bm3   = (const float*)d_in[20];
  const float* g1    = (const float*)d_in[21];
  const float* b1    = (const float*)d_in[22];
  const float* g2    = (const float*)d_in[23];
  const float* b2    = (const float*)d_in[24];

  float* ws   = (float*)d_ws;
  float* proj = ws;                               // NL*2016
  float* qt   = proj + (size_t)NL_*POUT_;         // 24*512*64
  float* kt   = qt   + (size_t)N_*H_*L_*64;       // 24*512*64
  float* vpg  = kt   + (size_t)N_*H_*L_*64;       // NL*288
  float* lgal = vpg  + (size_t)NL_*288;           // 24*512*512 (logits -> alpha)
  float* feat = lgal + (size_t)N_*H_*L_*L_;       // NL*1824
  float* ybuf = feat + (size_t)NL_*FEAT_;         // NL*128
  float* pav  = ybuf + (size_t)NL_*RD_;           // 8*24*512*56 (22MB)

  k_proj_gemm<<<dim3(NL_/8, 16), 256, 0, stream>>>(resf, Wq, Wk, Wv, Wqp, Wkp, Wvp, proj);
  k_rot<<<NL_, 64, 0, stream>>>(R, coord, spc, proj, qt, kt, vpg);
  k_lgns<<<dim3(L_/64, L_/128, N_*H_), 256, 0, stream>>>(qt, kt, lgal);
  k_pbsa<<<dim3(L_, N_), 256, 0, stream>>>(pair, mask, Wpb, lgal, feat);
  k_av<<<dim3(L_/64, N_*H_, 8), 256, 0, stream>>>(lgal, proj, vpg, pav);
  k_avred<<<NL_, 256, 0, stream>>>(pav, R, coord, feat);
  k_y_gemm<<<dim3(NL_/8, 2), 256, 0, stream>>>(feat, Wout, ybuf);
  k_mlp<<<NL_/4, 256, 0, stream>>>(resf, mask, ybuf, bout, Wm1, bm1, Wm2, bm2, Wm3, bm3,
                                   g1, b1, g2, b2, (float*)d_out);
}